// Round 1
// baseline (6256.039 us; speedup 1.0000x reference)
//
#include <hip/hip_runtime.h>
#include <math.h>

#define N_NODES 200000
#define N_EDGES 6400000
#define F_IN 128
#define NH 16
#define NC 2

// ws layout in floats
#define OFF_DINV 0                         // [N_NODES] deg -> dinv
#define OFF_H1   (N_NODES)                 // [N_NODES*16] h1 = x@W1 (no bias)
#define OFF_AGG1 (N_NODES + 16*N_NODES)    // [N_NODES*16]
#define OFF_H2   (N_NODES + 32*N_NODES)    // [N_NODES*2] h2lin = relu(out1)@W2
#define OFF_AGG2 (N_NODES + 34*N_NODES)    // [N_NODES*2]
#define OFF_FLAG (N_NODES + 36*N_NODES)    // [1] int: 1 => edge_index is int32
#define WS_FLOATS (OFF_FLAG + 1)

__global__ __launch_bounds__(256) void k_init(float* ws) {
    int i = blockIdx.x * blockDim.x + threadIdx.x;
    if (i < WS_FLOATS) ws[i] = (i < N_NODES) ? 1.0f : 0.0f;
}

// Detect whether edge buffer is int64 or int32. Read first 1024 entries as
// int64; if data is really int32 pairs, values will be >= 2^32 (out of range).
__global__ void k_detect(const void* edges, int* flag) {
    const long long* e64 = (const long long*)edges;
    bool bad = false;
    for (int j = threadIdx.x; j < 1024; j += 256) {
        long long v = e64[j];
        if (v < 0 || v >= N_NODES) bad = true;
    }
    if (bad) atomicOr(flag, 1);
}

__device__ __forceinline__ int load_idx(const void* edges, int is32, long long pos) {
    if (is32) return ((const int*)edges)[pos];
    return (int)((const long long*)edges)[pos];
}

__global__ __launch_bounds__(256) void k_deg(const void* edges, float* deg, const int* flag) {
    int e = blockIdx.x * blockDim.x + threadIdx.x;
    if (e >= N_EDGES) return;
    int is32 = *flag;
    int dst = load_idx(edges, is32, (long long)N_EDGES + e);
    atomicAdd(&deg[dst], 1.0f);
}

__global__ __launch_bounds__(256) void k_dinv(float* ws) {
    int i = blockIdx.x * blockDim.x + threadIdx.x;
    if (i < N_NODES) ws[i] = rsqrtf(ws[i]);
}

// h1 = x @ W1 : [200000,128] x [128,16]
__global__ __launch_bounds__(256) void k_gemm1(const float* __restrict__ x,
                                               const float* __restrict__ W1,
                                               float* __restrict__ h1) {
    __shared__ float sW[F_IN * NH];      // 128*16
    __shared__ float sX[16 * 132];       // 16 rows, padded stride 132
    int t = threadIdx.x;
    int row0 = blockIdx.x * 16;
    for (int j = t; j < F_IN * NH; j += 256) sW[j] = W1[j];
    // stage 16 rows x 128 floats = 512 float4
    for (int v = t; v < 512; v += 256) {
        int r = v >> 5;           // 32 float4 per row
        int q = v & 31;
        float4 val = ((const float4*)x)[(size_t)(row0 + r) * 32 + q];
        *((float4*)&sX[r * 132 + (q << 2)]) = val;
    }
    __syncthreads();
    int r = t >> 4, c = t & 15;
    float acc = 0.0f;
#pragma unroll 8
    for (int k = 0; k < F_IN; k++) acc += sX[r * 132 + k] * sW[k * NH + c];
    h1[(size_t)(row0 + r) * NH + c] = acc;
}

__global__ __launch_bounds__(256) void k_scatter1(const void* edges,
                                                  const float* __restrict__ dinv,
                                                  const float* __restrict__ h1,
                                                  float* agg1, const int* flag) {
    int e = blockIdx.x * blockDim.x + threadIdx.x;
    if (e >= N_EDGES) return;
    int is32 = *flag;
    int src, dst;
    if (is32) {
        const int* p = (const int*)edges;
        src = p[e]; dst = p[N_EDGES + e];
    } else {
        const long long* p = (const long long*)edges;
        src = (int)p[e]; dst = (int)p[(long long)N_EDGES + e];
    }
    float norm = dinv[src] * dinv[dst];
    const float4* hs = (const float4*)(h1 + (size_t)src * NH);
    float* ad = agg1 + (size_t)dst * NH;
#pragma unroll
    for (int q = 0; q < 4; q++) {
        float4 v = hs[q];
        atomicAdd(ad + q * 4 + 0, norm * v.x);
        atomicAdd(ad + q * 4 + 1, norm * v.y);
        atomicAdd(ad + q * 4 + 2, norm * v.z);
        atomicAdd(ad + q * 4 + 3, norm * v.w);
    }
}

// out1 = agg1 + dinv^2*h1 + b1 ; relu ; h2lin = relu(out1) @ W2
__global__ __launch_bounds__(256) void k_combine1(const float* __restrict__ dinv,
                                                  const float* __restrict__ h1,
                                                  const float* __restrict__ agg1,
                                                  const float* __restrict__ b1,
                                                  const float* __restrict__ W2,
                                                  float* __restrict__ h2lin) {
    int i = blockIdx.x * blockDim.x + threadIdx.x;
    if (i >= N_NODES) return;
    float di = dinv[i];
    float d2 = di * di;
    const float4* hp = (const float4*)(h1 + (size_t)i * NH);
    const float4* ap = (const float4*)(agg1 + (size_t)i * NH);
    float r[NH];
#pragma unroll
    for (int q = 0; q < 4; q++) {
        float4 h = hp[q];
        float4 a = ap[q];
        r[q * 4 + 0] = fmaxf(a.x + d2 * h.x + b1[q * 4 + 0], 0.0f);
        r[q * 4 + 1] = fmaxf(a.y + d2 * h.y + b1[q * 4 + 1], 0.0f);
        r[q * 4 + 2] = fmaxf(a.z + d2 * h.z + b1[q * 4 + 2], 0.0f);
        r[q * 4 + 3] = fmaxf(a.w + d2 * h.w + b1[q * 4 + 3], 0.0f);
    }
    float o0 = 0.0f, o1 = 0.0f;
#pragma unroll
    for (int f = 0; f < NH; f++) {
        o0 += r[f] * W2[f * 2 + 0];
        o1 += r[f] * W2[f * 2 + 1];
    }
    h2lin[(size_t)i * 2 + 0] = o0;
    h2lin[(size_t)i * 2 + 1] = o1;
}

__global__ __launch_bounds__(256) void k_scatter2(const void* edges,
                                                  const float* __restrict__ dinv,
                                                  const float* __restrict__ h2lin,
                                                  float* agg2, const int* flag) {
    int e = blockIdx.x * blockDim.x + threadIdx.x;
    if (e >= N_EDGES) return;
    int is32 = *flag;
    int src, dst;
    if (is32) {
        const int* p = (const int*)edges;
        src = p[e]; dst = p[N_EDGES + e];
    } else {
        const long long* p = (const long long*)edges;
        src = (int)p[e]; dst = (int)p[(long long)N_EDGES + e];
    }
    float norm = dinv[src] * dinv[dst];
    float2 v = *(const float2*)(h2lin + (size_t)src * 2);
    atomicAdd(agg2 + (size_t)dst * 2 + 0, norm * v.x);
    atomicAdd(agg2 + (size_t)dst * 2 + 1, norm * v.y);
}

__global__ __launch_bounds__(256) void k_final(const float* __restrict__ dinv,
                                               const float* __restrict__ h2lin,
                                               const float* __restrict__ agg2,
                                               const float* __restrict__ b2,
                                               float* __restrict__ out) {
    int i = blockIdx.x * blockDim.x + threadIdx.x;
    if (i >= N_NODES) return;
    float di = dinv[i];
    float d2 = di * di;
    float2 h = *(const float2*)(h2lin + (size_t)i * 2);
    float2 a = *(const float2*)(agg2 + (size_t)i * 2);
    float o0 = a.x + d2 * h.x + b2[0];
    float o1 = a.y + d2 * h.y + b2[1];
    float m = fmaxf(o0, o1);
    float lse = m + logf(expf(o0 - m) + expf(o1 - m));
    out[(size_t)i * 2 + 0] = o0 - lse;
    out[(size_t)i * 2 + 1] = o1 - lse;
}

extern "C" void kernel_launch(void* const* d_in, const int* in_sizes, int n_in,
                              void* d_out, int out_size, void* d_ws, size_t ws_size,
                              hipStream_t stream) {
    const float* x  = (const float*)d_in[0];
    const void*  ei = d_in[1];
    const float* W1 = (const float*)d_in[2];
    const float* b1 = (const float*)d_in[3];
    const float* W2 = (const float*)d_in[4];
    const float* b2 = (const float*)d_in[5];

    float* ws    = (float*)d_ws;
    float* dinv  = ws + OFF_DINV;
    float* h1    = ws + OFF_H1;
    float* agg1  = ws + OFF_AGG1;
    float* h2lin = ws + OFF_H2;
    float* agg2  = ws + OFF_AGG2;
    int*   flag  = (int*)(ws + OFF_FLAG);

    float* out = (float*)d_out;

    k_init<<<(WS_FLOATS + 255) / 256, 256, 0, stream>>>(ws);
    k_detect<<<1, 256, 0, stream>>>(ei, flag);
    k_deg<<<N_EDGES / 256, 256, 0, stream>>>(ei, dinv, flag);
    k_dinv<<<(N_NODES + 255) / 256, 256, 0, stream>>>(dinv);
    k_gemm1<<<N_NODES / 16, 256, 0, stream>>>(x, W1, h1);
    k_scatter1<<<N_EDGES / 256, 256, 0, stream>>>(ei, dinv, h1, agg1, flag);
    k_combine1<<<(N_NODES + 255) / 256, 256, 0, stream>>>(dinv, h1, agg1, b1, W2, h2lin);
    k_scatter2<<<N_EDGES / 256, 256, 0, stream>>>(ei, dinv, h2lin, agg2, flag);
    k_final<<<(N_NODES + 255) / 256, 256, 0, stream>>>(dinv, h2lin, agg2, b2, out);
}

// Round 2
// 1135.553 us; speedup vs baseline: 5.5092x; 5.5092x over previous
//
#include <hip/hip_runtime.h>
#include <math.h>

#define N_NODES 200000
#define N_EDGES 6400000
#define F_IN 128
#define NH 16
#define NC 2
#define NBLK_SCAN 782   // ceil(200000/256)

// ws layout in 4-byte words
#define OFF_DINV     0                      // [N] float
#define OFF_ROWSTART 200000                 // [N+1] int
#define OFF_CURSOR   400001                 // [N] int
#define OFF_COUNTS   600001                 // [N] int
#define OFF_BLKSUM   800001                 // [1024] int
#define OFF_FLAG     801025                 // [1] int
#define OFF_CSR      801028                 // [E] int (pad to 16B alignment)
#define OFF_H1       7201028                // [16N] float (16B-aligned)
#define OFF_H2       10401028               // [2N] float (8B-aligned)

__global__ __launch_bounds__(256) void k_init(int* counts, int* flag) {
    int i = blockIdx.x * blockDim.x + threadIdx.x;
    if (i < N_NODES) counts[i] = 0;
    if (i == 0) *flag = 0;
}

// Detect int64 vs int32 edge buffer: read first 1024 entries as int64;
// int32 data reinterpreted as int64 lands out of [0, N_NODES) w.h.p.
__global__ void k_detect(const void* edges, int* flag) {
    const long long* e64 = (const long long*)edges;
    bool bad = false;
    for (int j = threadIdx.x; j < 1024; j += 256) {
        long long v = e64[j];
        if (v < 0 || v >= N_NODES) bad = true;
    }
    if (bad) atomicOr(flag, 1);
}

__global__ __launch_bounds__(256) void k_deg(const void* edges, int* counts, const int* flag) {
    int e = blockIdx.x * blockDim.x + threadIdx.x;
    if (e >= N_EDGES) return;
    int is32 = *flag;
    int dst;
    if (is32) dst = ((const int*)edges)[N_EDGES + e];
    else      dst = (int)((const long long*)edges)[(long long)N_EDGES + e];
    atomicAdd(&counts[dst], 1);
}

// block-level inclusive scan of counts -> row_start (inclusive, local); block sums out
__global__ __launch_bounds__(256) void k_scan1(const int* __restrict__ counts,
                                               int* __restrict__ row_start,
                                               int* __restrict__ blkSums) {
    __shared__ int s[2][256];
    int t = threadIdx.x;
    int i = blockIdx.x * 256 + t;
    int v = (i < N_NODES) ? counts[i] : 0;
    s[0][t] = v;
    __syncthreads();
    int cur = 0;
    for (int off = 1; off < 256; off <<= 1) {
        int nv = s[cur][t];
        if (t >= off) nv += s[cur][t - off];
        s[cur ^ 1][t] = nv;
        cur ^= 1;
        __syncthreads();
    }
    int incl = s[cur][t];
    if (i < N_NODES) row_start[i] = incl;
    if (t == 255) blkSums[blockIdx.x] = incl;
}

// exclusive scan of the 782 block sums, in place (one block of 1024)
__global__ __launch_bounds__(1024) void k_scan2(int* blkSums) {
    __shared__ int s[2][1024];
    int t = threadIdx.x;
    int v = (t < NBLK_SCAN) ? blkSums[t] : 0;
    s[0][t] = v;
    __syncthreads();
    int cur = 0;
    for (int off = 1; off < 1024; off <<= 1) {
        int nv = s[cur][t];
        if (t >= off) nv += s[cur][t - off];
        s[cur ^ 1][t] = nv;
        cur ^= 1;
        __syncthreads();
    }
    if (t < NBLK_SCAN) blkSums[t] = s[cur][t] - v;   // exclusive
}

// finalize: row_start -> global exclusive; cursor copy; dinv = rsqrt(deg+1)
__global__ __launch_bounds__(256) void k_scan3(int* __restrict__ row_start,
                                               int* __restrict__ cursor,
                                               const int* __restrict__ counts,
                                               const int* __restrict__ blkSums,
                                               float* __restrict__ dinv) {
    int i = blockIdx.x * blockDim.x + threadIdx.x;
    if (i >= N_NODES) return;
    int c = counts[i];
    int excl = row_start[i] - c + blkSums[i >> 8];
    row_start[i] = excl;
    cursor[i] = excl;
    dinv[i] = rsqrtf((float)c + 1.0f);
    if (i == 0) row_start[N_NODES] = N_EDGES;
}

__global__ __launch_bounds__(256) void k_csr_fill(const void* edges, int* cursor,
                                                  int* __restrict__ csr_src, const int* flag) {
    int e = blockIdx.x * blockDim.x + threadIdx.x;
    if (e >= N_EDGES) return;
    int is32 = *flag;
    int src, dst;
    if (is32) {
        const int* p = (const int*)edges;
        src = p[e]; dst = p[N_EDGES + e];
    } else {
        const long long* p = (const long long*)edges;
        src = (int)p[e]; dst = (int)p[(long long)N_EDGES + e];
    }
    int pos = atomicAdd(&cursor[dst], 1);
    csr_src[pos] = src;
}

// h1 = x @ W1 : [200000,128] x [128,16]
__global__ __launch_bounds__(256) void k_gemm1(const float* __restrict__ x,
                                               const float* __restrict__ W1,
                                               float* __restrict__ h1) {
    __shared__ float sW[F_IN * NH];
    __shared__ float sX[16 * 132];
    int t = threadIdx.x;
    int row0 = blockIdx.x * 16;
    for (int j = t; j < F_IN * NH; j += 256) sW[j] = W1[j];
    for (int v = t; v < 512; v += 256) {
        int r = v >> 5;
        int q = v & 31;
        float4 val = ((const float4*)x)[(size_t)(row0 + r) * 32 + q];
        *((float4*)&sX[r * 132 + (q << 2)]) = val;
    }
    __syncthreads();
    int r = t >> 4, c = t & 15;
    float acc = 0.0f;
#pragma unroll 8
    for (int k = 0; k < F_IN; k++) acc += sX[r * 132 + k] * sW[k * NH + c];
    h1[(size_t)(row0 + r) * NH + c] = acc;
}

// per node: gather agg1, + self-loop + b1, relu, times W2 -> h2lin. 16 lanes/node.
__global__ __launch_bounds__(256) void k_gather1(const int* __restrict__ row_start,
                                                 const int* __restrict__ csr_src,
                                                 const float* __restrict__ dinv,
                                                 const float* __restrict__ h1,
                                                 const float* __restrict__ b1,
                                                 const float* __restrict__ W2,
                                                 float* __restrict__ h2) {
    int t = threadIdx.x;
    int i = blockIdx.x * 16 + (t >> 4);
    int l = t & 15;
    int start = row_start[i];
    int end = row_start[i + 1];
    float di = dinv[i];
    float acc = 0.0f;
    for (int e = start; e < end; ++e) {
        int src = csr_src[e];
        float nrm = dinv[src] * di;
        acc += nrm * h1[(size_t)src * NH + l];
    }
    float r = fmaxf(acc + di * di * h1[(size_t)i * NH + l] + b1[l], 0.0f);
    float v0 = r * W2[l * 2 + 0];
    float v1 = r * W2[l * 2 + 1];
#pragma unroll
    for (int m = 8; m >= 1; m >>= 1) {
        v0 += __shfl_xor(v0, m, 16);
        v1 += __shfl_xor(v1, m, 16);
    }
    if (l == 0) {
        h2[(size_t)i * 2 + 0] = v0;
        h2[(size_t)i * 2 + 1] = v1;
    }
}

// per node: gather agg2 (4 lanes/node, edge-parallel), + self-loop + b2, log_softmax
__global__ __launch_bounds__(256) void k_gather2(const int* __restrict__ row_start,
                                                 const int* __restrict__ csr_src,
                                                 const float* __restrict__ dinv,
                                                 const float* __restrict__ h2,
                                                 const float* __restrict__ b2,
                                                 float* __restrict__ out) {
    int t = threadIdx.x;
    int i = blockIdx.x * 64 + (t >> 2);
    int l = t & 3;
    int start = row_start[i];
    int end = row_start[i + 1];
    float di = dinv[i];
    float o0 = 0.0f, o1 = 0.0f;
    for (int e = start + l; e < end; e += 4) {
        int src = csr_src[e];
        float nrm = dinv[src] * di;
        float2 hv = *(const float2*)(h2 + (size_t)src * 2);
        o0 += nrm * hv.x;
        o1 += nrm * hv.y;
    }
    o0 += __shfl_xor(o0, 2, 4); o0 += __shfl_xor(o0, 1, 4);
    o1 += __shfl_xor(o1, 2, 4); o1 += __shfl_xor(o1, 1, 4);
    if (l == 0) {
        float d2 = di * di;
        float2 hv = *(const float2*)(h2 + (size_t)i * 2);
        float f0 = o0 + d2 * hv.x + b2[0];
        float f1 = o1 + d2 * hv.y + b2[1];
        float m = fmaxf(f0, f1);
        float lse = m + logf(expf(f0 - m) + expf(f1 - m));
        out[(size_t)i * 2 + 0] = f0 - lse;
        out[(size_t)i * 2 + 1] = f1 - lse;
    }
}

extern "C" void kernel_launch(void* const* d_in, const int* in_sizes, int n_in,
                              void* d_out, int out_size, void* d_ws, size_t ws_size,
                              hipStream_t stream) {
    const float* x  = (const float*)d_in[0];
    const void*  ei = d_in[1];
    const float* W1 = (const float*)d_in[2];
    const float* b1 = (const float*)d_in[3];
    const float* W2 = (const float*)d_in[4];
    const float* b2 = (const float*)d_in[5];

    int*   wsw      = (int*)d_ws;
    float* dinv     = (float*)(wsw + OFF_DINV);
    int*   row_start= wsw + OFF_ROWSTART;
    int*   cursor   = wsw + OFF_CURSOR;
    int*   counts   = wsw + OFF_COUNTS;
    int*   blkSums  = wsw + OFF_BLKSUM;
    int*   flag     = wsw + OFF_FLAG;
    int*   csr_src  = wsw + OFF_CSR;
    float* h1       = (float*)(wsw + OFF_H1);
    float* h2       = (float*)(wsw + OFF_H2);
    float* out      = (float*)d_out;

    k_init<<<(N_NODES + 255) / 256, 256, 0, stream>>>(counts, flag);
    k_detect<<<1, 256, 0, stream>>>(ei, flag);
    k_deg<<<N_EDGES / 256, 256, 0, stream>>>(ei, counts, flag);
    k_scan1<<<NBLK_SCAN, 256, 0, stream>>>(counts, row_start, blkSums);
    k_scan2<<<1, 1024, 0, stream>>>(blkSums);
    k_scan3<<<(N_NODES + 255) / 256, 256, 0, stream>>>(row_start, cursor, counts, blkSums, dinv);
    k_csr_fill<<<N_EDGES / 256, 256, 0, stream>>>(ei, cursor, csr_src, flag);
    k_gemm1<<<N_NODES / 16, 256, 0, stream>>>(x, W1, h1);
    k_gather1<<<N_NODES / 16, 256, 0, stream>>>(row_start, csr_src, dinv, h1, b1, W2, h2);
    k_gather2<<<N_NODES / 64, 256, 0, stream>>>(row_start, csr_src, dinv, h2, b2, out);
}

// Round 3
// 448.760 us; speedup vs baseline: 13.9407x; 2.5304x over previous
//
#include <hip/hip_runtime.h>
#include <math.h>

#define N_NODES 200000
#define N_EDGES 6400000
#define F_IN 128
#define NH 16
#define NB 196          // ceil(200000/1024) buckets of 1024 nodes
#define CH 8192         // edges per chunk in bucket passes
#define NCHUNK 782      // ceil(6400000/8192)
#define BKT_CAP 36352   // LDS stage capacity per bucket (mean 32768, +19 sigma)

// ws layout in 4-byte words. ebuf (packed edges) is reused in-place as csr_src.
#define OFF_DINV    0            // [N] float
#define OFF_ROW     200000       // [N+1] int
#define OFF_BCOUNT  400004       // [256] int
#define OFF_BBASE   400260       // [256] int
#define OFF_BCURSOR 400520       // [256] int
#define OFF_FLAG    400776       // [1] int
#define OFF_EBUF    400784       // [E] u32 packed (dst_local<<18)|src ; later csr_src
#define OFF_H1      6800784      // [16N] float
#define OFF_H2      10000784     // [2N] float

__global__ __launch_bounds__(256) void k_init(int* bcount, int* flag) {
    int t = blockIdx.x * 256 + threadIdx.x;
    if (t < 256) bcount[t] = 0;
    if (t == 0) *flag = 0;
}

// int64 vs int32 edge buffer detection
__global__ void k_detect(const void* edges, int* flag) {
    const long long* e64 = (const long long*)edges;
    bool bad = false;
    for (int j = threadIdx.x; j < 1024; j += 256) {
        long long v = e64[j];
        if (v < 0 || v >= N_NODES) bad = true;
    }
    if (bad) atomicOr(flag, 1);
}

__global__ __launch_bounds__(256) void k_bhist(const void* edges, const int* flag,
                                               int* bcount) {
    __shared__ int sH[256];
    int t = threadIdx.x;
    sH[t] = 0;
    __syncthreads();
    long long e0 = (long long)blockIdx.x * CH;
    int nloc = (int)min((long long)CH, (long long)N_EDGES - e0);
    int is32 = *flag;
    for (int j = t; j < nloc; j += 256) {
        long long e = e0 + j;
        int dst = is32 ? ((const int*)edges)[N_EDGES + e]
                       : (int)((const long long*)edges)[(long long)N_EDGES + e];
        atomicAdd(&sH[dst >> 10], 1);
    }
    __syncthreads();
    if (sH[t]) atomicAdd(&bcount[t], sH[t]);
}

// single block: exclusive scan of 256 bucket counts -> bbase, bcursor; row_start[N]=E
__global__ __launch_bounds__(256) void k_bscan(const int* __restrict__ bcount,
                                               int* __restrict__ bbase,
                                               int* __restrict__ bcursor,
                                               int* __restrict__ row_start) {
    __shared__ int s[2][256];
    int t = threadIdx.x;
    int v = bcount[t];
    s[0][t] = v;
    __syncthreads();
    int cur = 0;
    for (int off = 1; off < 256; off <<= 1) {
        int nv = s[cur][t];
        if (t >= off) nv += s[cur][t - off];
        s[cur ^ 1][t] = nv;
        cur ^= 1;
        __syncthreads();
    }
    int excl = s[cur][t] - v;
    bbase[t] = excl;
    bcursor[t] = excl;
    if (t == 0) row_start[N_NODES] = N_EDGES;
}

// block-local counting by bucket; one global reservation atomic per (block,bucket);
// scatter packed u32 into per-bucket streams (L2 write-combined runs)
__global__ __launch_bounds__(256) void k_bscatter(const void* edges, const int* flag,
                                                  int* bcursor, unsigned* ebuf) {
    __shared__ unsigned sP[CH];
    __shared__ unsigned short sB[CH];
    __shared__ int sH[256];
    __shared__ int sGbase[256];
    int t = threadIdx.x;
    sH[t] = 0;
    __syncthreads();
    long long e0 = (long long)blockIdx.x * CH;
    int nloc = (int)min((long long)CH, (long long)N_EDGES - e0);
    int is32 = *flag;
    for (int j = t; j < nloc; j += 256) {
        long long e = e0 + j;
        int src, dst;
        if (is32) {
            src = ((const int*)edges)[e];
            dst = ((const int*)edges)[N_EDGES + e];
        } else {
            src = (int)((const long long*)edges)[e];
            dst = (int)((const long long*)edges)[(long long)N_EDGES + e];
        }
        int b = dst >> 10;
        sP[j] = (unsigned)(((dst & 1023) << 18) | src);
        sB[j] = (unsigned short)b;
        atomicAdd(&sH[b], 1);
    }
    __syncthreads();
    if (sH[t] > 0) sGbase[t] = atomicAdd(&bcursor[t], sH[t]);
    __syncthreads();
    sH[t] = 0;   // reuse as local rank cursor
    __syncthreads();
    for (int j = t; j < nloc; j += 256) {
        int b = sB[j];
        int r = atomicAdd(&sH[b], 1);
        ebuf[sGbase[b] + r] = sP[j];
    }
}

// one block per bucket: stage edges in LDS, 1024-bin count+scan -> row_start/dinv,
// then ranked scatter writes csr_src IN PLACE over ebuf (same [base,end) range).
__global__ __launch_bounds__(1024) void k_bsort(unsigned* ebuf,
                                                const int* __restrict__ bbase,
                                                int* __restrict__ row_start,
                                                float* __restrict__ dinv) {
    __shared__ unsigned sE[BKT_CAP];
    __shared__ int sH[1024];
    __shared__ int sS[2][1024];
    int b = blockIdx.x, t = threadIdx.x;
    int base = bbase[b];
    int end = bbase[b + 1];
    int cnt = end - base;
    int cap = cnt < BKT_CAP ? cnt : BKT_CAP;
    for (int j = t; j < cap; j += 1024) sE[j] = ebuf[base + j];
    sH[t] = 0;
    __syncthreads();
    for (int j = t; j < cnt; j += 1024) {
        unsigned p = (j < cap) ? sE[j] : ebuf[base + j];
        atomicAdd(&sH[p >> 18], 1);
    }
    __syncthreads();
    int v = sH[t];
    sS[0][t] = v;
    __syncthreads();
    int cur = 0;
    for (int off = 1; off < 1024; off <<= 1) {
        int nv = sS[cur][t];
        if (t >= off) nv += sS[cur][t - off];
        sS[cur ^ 1][t] = nv;
        cur ^= 1;
        __syncthreads();
    }
    int excl = sS[cur][t] - v;
    int node = b * 1024 + t;
    if (node < N_NODES) {
        row_start[node] = base + excl;
        dinv[node] = rsqrtf((float)v + 1.0f);
    }
    __syncthreads();
    sH[t] = excl;   // reuse as cursor
    __syncthreads();
    for (int j = t; j < cnt; j += 1024) {
        unsigned p = (j < cap) ? sE[j] : ebuf[base + j];
        int dl = p >> 18;
        int pos = atomicAdd(&sH[dl], 1);
        ebuf[base + pos] = p & 0x3FFFF;   // in-place: staged copy read first
    }
}

// h1 = x @ W1 : [200000,128] x [128,16]
__global__ __launch_bounds__(256) void k_gemm1(const float* __restrict__ x,
                                               const float* __restrict__ W1,
                                               float* __restrict__ h1) {
    __shared__ float sW[F_IN * NH];
    __shared__ float sX[16 * 132];
    int t = threadIdx.x;
    int row0 = blockIdx.x * 16;
    for (int j = t; j < F_IN * NH; j += 256) sW[j] = W1[j];
    for (int v = t; v < 512; v += 256) {
        int r = v >> 5;
        int q = v & 31;
        float4 val = ((const float4*)x)[(size_t)(row0 + r) * 32 + q];
        *((float4*)&sX[r * 132 + (q << 2)]) = val;
    }
    __syncthreads();
    int r = t >> 4, c = t & 15;
    float acc = 0.0f;
#pragma unroll 8
    for (int k = 0; k < F_IN; k++) acc += sX[r * 132 + k] * sW[k * NH + c];
    h1[(size_t)(row0 + r) * NH + c] = acc;
}

// per node: gather agg1, + self-loop + b1, relu, x W2 -> h2. 16 lanes/node.
__global__ __launch_bounds__(256) void k_gather1(const int* __restrict__ row_start,
                                                 const int* __restrict__ csr_src,
                                                 const float* __restrict__ dinv,
                                                 const float* __restrict__ h1,
                                                 const float* __restrict__ b1,
                                                 const float* __restrict__ W2,
                                                 float* __restrict__ h2) {
    int t = threadIdx.x;
    int i = blockIdx.x * 16 + (t >> 4);
    int l = t & 15;
    int start = row_start[i];
    int end = row_start[i + 1];
    float di = dinv[i];
    float acc = 0.0f;
    for (int e = start; e < end; ++e) {
        int src = csr_src[e];
        float nrm = dinv[src] * di;
        acc += nrm * h1[(size_t)src * NH + l];
    }
    float r = fmaxf(acc + di * di * h1[(size_t)i * NH + l] + b1[l], 0.0f);
    float v0 = r * W2[l * 2 + 0];
    float v1 = r * W2[l * 2 + 1];
#pragma unroll
    for (int m = 8; m >= 1; m >>= 1) {
        v0 += __shfl_xor(v0, m, 16);
        v1 += __shfl_xor(v1, m, 16);
    }
    if (l == 0) {
        h2[(size_t)i * 2 + 0] = v0;
        h2[(size_t)i * 2 + 1] = v1;
    }
}

// per node: gather agg2 (4 lanes/node), + self-loop + b2, log_softmax
__global__ __launch_bounds__(256) void k_gather2(const int* __restrict__ row_start,
                                                 const int* __restrict__ csr_src,
                                                 const float* __restrict__ dinv,
                                                 const float* __restrict__ h2,
                                                 const float* __restrict__ b2,
                                                 float* __restrict__ out) {
    int t = threadIdx.x;
    int i = blockIdx.x * 64 + (t >> 2);
    int l = t & 3;
    int start = row_start[i];
    int end = row_start[i + 1];
    float di = dinv[i];
    float o0 = 0.0f, o1 = 0.0f;
    for (int e = start + l; e < end; e += 4) {
        int src = csr_src[e];
        float nrm = dinv[src] * di;
        float2 hv = *(const float2*)(h2 + (size_t)src * 2);
        o0 += nrm * hv.x;
        o1 += nrm * hv.y;
    }
    o0 += __shfl_xor(o0, 2, 4); o0 += __shfl_xor(o0, 1, 4);
    o1 += __shfl_xor(o1, 2, 4); o1 += __shfl_xor(o1, 1, 4);
    if (l == 0) {
        float d2 = di * di;
        float2 hv = *(const float2*)(h2 + (size_t)i * 2);
        float f0 = o0 + d2 * hv.x + b2[0];
        float f1 = o1 + d2 * hv.y + b2[1];
        float m = fmaxf(f0, f1);
        float lse = m + logf(expf(f0 - m) + expf(f1 - m));
        out[(size_t)i * 2 + 0] = f0 - lse;
        out[(size_t)i * 2 + 1] = f1 - lse;
    }
}

extern "C" void kernel_launch(void* const* d_in, const int* in_sizes, int n_in,
                              void* d_out, int out_size, void* d_ws, size_t ws_size,
                              hipStream_t stream) {
    const float* x  = (const float*)d_in[0];
    const void*  ei = d_in[1];
    const float* W1 = (const float*)d_in[2];
    const float* b1 = (const float*)d_in[3];
    const float* W2 = (const float*)d_in[4];
    const float* b2 = (const float*)d_in[5];

    int*      wsw       = (int*)d_ws;
    float*    dinv      = (float*)(wsw + OFF_DINV);
    int*      row_start = wsw + OFF_ROW;
    int*      bcount    = wsw + OFF_BCOUNT;
    int*      bbase     = wsw + OFF_BBASE;
    int*      bcursor   = wsw + OFF_BCURSOR;
    int*      flag      = wsw + OFF_FLAG;
    unsigned* ebuf      = (unsigned*)(wsw + OFF_EBUF);   // becomes csr_src
    float*    h1        = (float*)(wsw + OFF_H1);
    float*    h2        = (float*)(wsw + OFF_H2);
    float*    out       = (float*)d_out;

    k_init<<<1, 256, 0, stream>>>(bcount, flag);
    k_detect<<<1, 256, 0, stream>>>(ei, flag);
    k_bhist<<<NCHUNK, 256, 0, stream>>>(ei, flag, bcount);
    k_bscan<<<1, 256, 0, stream>>>(bcount, bbase, bcursor, row_start);
    k_bscatter<<<NCHUNK, 256, 0, stream>>>(ei, flag, bcursor, ebuf);
    k_bsort<<<NB, 1024, 0, stream>>>(ebuf, bbase, row_start, dinv);
    k_gemm1<<<N_NODES / 16, 256, 0, stream>>>(x, W1, h1);
    k_gather1<<<N_NODES / 16, 256, 0, stream>>>(row_start, (const int*)ebuf, dinv, h1, b1, W2, h2);
    k_gather2<<<N_NODES / 64, 256, 0, stream>>>(row_start, (const int*)ebuf, dinv, h2, b2, out);
}

// Round 4
// 308.687 us; speedup vs baseline: 20.2666x; 1.4538x over previous
//
#include <hip/hip_runtime.h>
#include <math.h>

#define N_NODES 200000
#define N_EDGES 6400000
#define F_IN 128
#define NH 16
#define NB 196          // ceil(200000/1024) buckets of 1024 nodes
#define CH 8192         // edges per chunk in bucket passes
#define NCHUNK 782      // ceil(6400000/8192)
#define BKT_CAP 36352   // LDS stage capacity per bucket

// ws layout in 4-byte words. ebuf (packed edges) is reused in-place as csr_src.
#define OFF_DINV    0            // [N] float
#define OFF_ROW     200000       // [N+1] int
#define OFF_BCOUNT  400004       // [256] int
#define OFF_BBASE   400260       // [256] int
#define OFF_BCURSOR 400520       // [256] int
#define OFF_FLAG    400776       // [1] int
#define OFF_EBUF    400784       // [E] u32 packed (dst_local<<18)|src ; later csr_src
#define OFF_H1B     6800784      // [8N words] bf16 h1b[N][16] (= dinv*h1)
#define OFF_H2B     8400784      // [2N] float h2b (= dinv*h2)

__device__ __forceinline__ unsigned bf16rne(float f) {
    unsigned u = __float_as_uint(f);
    unsigned r = ((u >> 16) & 1u) + 0x7FFFu;
    return (u + r) >> 16;
}

__global__ __launch_bounds__(256) void k_init(int* bcount, int* flag) {
    int t = blockIdx.x * 256 + threadIdx.x;
    if (t < 256) bcount[t] = 0;
    if (t == 0) *flag = 0;
}

// int64 vs int32 edge buffer detection
__global__ void k_detect(const void* edges, int* flag) {
    const long long* e64 = (const long long*)edges;
    bool bad = false;
    for (int j = threadIdx.x; j < 1024; j += 256) {
        long long v = e64[j];
        if (v < 0 || v >= N_NODES) bad = true;
    }
    if (bad) atomicOr(flag, 1);
}

__global__ __launch_bounds__(256) void k_bhist(const void* edges, const int* flag,
                                               int* bcount) {
    __shared__ int sH[256];
    int t = threadIdx.x;
    sH[t] = 0;
    __syncthreads();
    long long e0 = (long long)blockIdx.x * CH;
    int nloc = (int)min((long long)CH, (long long)N_EDGES - e0);
    int is32 = *flag;
    for (int j = t; j < nloc; j += 256) {
        long long e = e0 + j;
        int dst = is32 ? ((const int*)edges)[N_EDGES + e]
                       : (int)((const long long*)edges)[(long long)N_EDGES + e];
        atomicAdd(&sH[dst >> 10], 1);
    }
    __syncthreads();
    if (sH[t]) atomicAdd(&bcount[t], sH[t]);
}

// single block: exclusive scan of 256 bucket counts -> bbase, bcursor; row_start[N]=E
__global__ __launch_bounds__(256) void k_bscan(const int* __restrict__ bcount,
                                               int* __restrict__ bbase,
                                               int* __restrict__ bcursor,
                                               int* __restrict__ row_start) {
    __shared__ int s[2][256];
    int t = threadIdx.x;
    int v = bcount[t];
    s[0][t] = v;
    __syncthreads();
    int cur = 0;
    for (int off = 1; off < 256; off <<= 1) {
        int nv = s[cur][t];
        if (t >= off) nv += s[cur][t - off];
        s[cur ^ 1][t] = nv;
        cur ^= 1;
        __syncthreads();
    }
    int excl = s[cur][t] - v;
    bbase[t] = excl;
    bcursor[t] = excl;
    if (t == 0) row_start[N_NODES] = N_EDGES;
}

// block-local counting by bucket; one global reservation atomic per (block,bucket);
// scatter packed u32 into per-bucket streams
__global__ __launch_bounds__(256) void k_bscatter(const void* edges, const int* flag,
                                                  int* bcursor, unsigned* ebuf) {
    __shared__ unsigned sP[CH];
    __shared__ unsigned short sB[CH];
    __shared__ int sH[256];
    __shared__ int sGbase[256];
    int t = threadIdx.x;
    sH[t] = 0;
    __syncthreads();
    long long e0 = (long long)blockIdx.x * CH;
    int nloc = (int)min((long long)CH, (long long)N_EDGES - e0);
    int is32 = *flag;
    for (int j = t; j < nloc; j += 256) {
        long long e = e0 + j;
        int src, dst;
        if (is32) {
            src = ((const int*)edges)[e];
            dst = ((const int*)edges)[N_EDGES + e];
        } else {
            src = (int)((const long long*)edges)[e];
            dst = (int)((const long long*)edges)[(long long)N_EDGES + e];
        }
        int b = dst >> 10;
        sP[j] = (unsigned)(((dst & 1023) << 18) | src);
        sB[j] = (unsigned short)b;
        atomicAdd(&sH[b], 1);
    }
    __syncthreads();
    if (sH[t] > 0) sGbase[t] = atomicAdd(&bcursor[t], sH[t]);
    __syncthreads();
    sH[t] = 0;   // reuse as local rank cursor
    __syncthreads();
    for (int j = t; j < nloc; j += 256) {
        int b = sB[j];
        int r = atomicAdd(&sH[b], 1);
        ebuf[sGbase[b] + r] = sP[j];
    }
}

// one block per bucket: stage edges in LDS, 1024-bin count+scan -> row_start/dinv,
// then ranked scatter writes csr_src IN PLACE over ebuf.
__global__ __launch_bounds__(1024) void k_bsort(unsigned* ebuf,
                                                const int* __restrict__ bbase,
                                                int* __restrict__ row_start,
                                                float* __restrict__ dinv) {
    __shared__ unsigned sE[BKT_CAP];
    __shared__ int sH[1024];
    __shared__ int sS[2][1024];
    int b = blockIdx.x, t = threadIdx.x;
    int base = bbase[b];
    int end = bbase[b + 1];
    int cnt = end - base;
    int cap = cnt < BKT_CAP ? cnt : BKT_CAP;
    for (int j = t; j < cap; j += 1024) sE[j] = ebuf[base + j];
    sH[t] = 0;
    __syncthreads();
    for (int j = t; j < cnt; j += 1024) {
        unsigned p = (j < cap) ? sE[j] : ebuf[base + j];
        atomicAdd(&sH[p >> 18], 1);
    }
    __syncthreads();
    int v = sH[t];
    sS[0][t] = v;
    __syncthreads();
    int cur = 0;
    for (int off = 1; off < 1024; off <<= 1) {
        int nv = sS[cur][t];
        if (t >= off) nv += sS[cur][t - off];
        sS[cur ^ 1][t] = nv;
        cur ^= 1;
        __syncthreads();
    }
    int excl = sS[cur][t] - v;
    int node = b * 1024 + t;
    if (node < N_NODES) {
        row_start[node] = base + excl;
        dinv[node] = rsqrtf((float)v + 1.0f);
    }
    __syncthreads();
    sH[t] = excl;   // reuse as cursor
    __syncthreads();
    for (int j = t; j < cnt; j += 1024) {
        unsigned p = (j < cap) ? sE[j] : ebuf[base + j];
        int dl = p >> 18;
        int pos = atomicAdd(&sH[dl], 1);
        ebuf[base + pos] = p & 0x3FFFF;
    }
}

// h1b = dinv * (x @ W1), stored bf16. One row per thread; W1^T in LDS,
// inner reads are wave-broadcast (conflict-free).
__global__ __launch_bounds__(256) void k_gemm1(const float* __restrict__ x,
                                               const float* __restrict__ W1,
                                               const float* __restrict__ dinv,
                                               unsigned short* __restrict__ h1b) {
    __shared__ float sWt[NH * F_IN];   // [c][k]
    int t = threadIdx.x;
    for (int q = t; q < 512; q += 256) {         // 512 float4 = 2048 floats
        float4 w = ((const float4*)W1)[q];
        int k = q >> 2, c0 = (q & 3) * 4;
        sWt[(c0 + 0) * F_IN + k] = w.x;
        sWt[(c0 + 1) * F_IN + k] = w.y;
        sWt[(c0 + 2) * F_IN + k] = w.z;
        sWt[(c0 + 3) * F_IN + k] = w.w;
    }
    __syncthreads();
    int row = blockIdx.x * 256 + t;
    if (row >= N_NODES) return;
    float acc[NH];
#pragma unroll
    for (int c = 0; c < NH; c++) acc[c] = 0.0f;
    const float4* xr = (const float4*)(x + (size_t)row * F_IN);
    for (int kq = 0; kq < F_IN / 4; kq++) {
        float4 xv = xr[kq];
#pragma unroll
        for (int c = 0; c < NH; c++) {
            float4 wv = *(const float4*)&sWt[c * F_IN + (kq << 2)];
            acc[c] += xv.x * wv.x + xv.y * wv.y + xv.z * wv.z + xv.w * wv.w;
        }
    }
    float di = dinv[row];
    uint4 p0, p1;
    unsigned pk[8];
#pragma unroll
    for (int j = 0; j < 8; j++)
        pk[j] = bf16rne(acc[2 * j] * di) | (bf16rne(acc[2 * j + 1] * di) << 16);
    p0 = make_uint4(pk[0], pk[1], pk[2], pk[3]);
    p1 = make_uint4(pk[4], pk[5], pk[6], pk[7]);
    uint4* dst = (uint4*)(h1b + (size_t)row * NH);
    dst[0] = p0;
    dst[1] = p1;
}

// gather1: 16 lanes/node = 4 edge-slots x 4 feature-quads. Pure add inner loop.
// out1 = di*(sum_src h1b[src] + h1b[i]) + b1; relu; h2 = out1 @ W2; h2b = di*h2.
__global__ __launch_bounds__(256) void k_gather1(const int* __restrict__ row_start,
                                                 const int* __restrict__ csr_src,
                                                 const float* __restrict__ dinv,
                                                 const unsigned short* __restrict__ h1b,
                                                 const float* __restrict__ b1,
                                                 const float* __restrict__ W2,
                                                 float* __restrict__ h2b) {
    int t = threadIdx.x;
    int i = blockIdx.x * 16 + (t >> 4);
    int fq = t & 3;
    int slot = (t >> 2) & 3;
    int start = row_start[i];
    int end = row_start[i + 1];
    float di = dinv[i];
    float4 acc = make_float4(0.f, 0.f, 0.f, 0.f);
    for (int e = start + slot; e < end; e += 4) {
        int src = csr_src[e];
        uint2 v = *(const uint2*)(h1b + ((size_t)src << 4) + (fq << 2));
        acc.x += __uint_as_float(v.x << 16);
        acc.y += __uint_as_float(v.x & 0xFFFF0000u);
        acc.z += __uint_as_float(v.y << 16);
        acc.w += __uint_as_float(v.y & 0xFFFF0000u);
    }
    // reduce over the 4 edge slots (lanes differ in bits 2..3 of the 16-group)
    acc.x += __shfl_xor(acc.x, 4, 16);
    acc.y += __shfl_xor(acc.y, 4, 16);
    acc.z += __shfl_xor(acc.z, 4, 16);
    acc.w += __shfl_xor(acc.w, 4, 16);
    acc.x += __shfl_xor(acc.x, 8, 16);
    acc.y += __shfl_xor(acc.y, 8, 16);
    acc.z += __shfl_xor(acc.z, 8, 16);
    acc.w += __shfl_xor(acc.w, 8, 16);
    float v0 = 0.f, v1 = 0.f;
    if (slot == 0) {
        uint2 sv = *(const uint2*)(h1b + ((size_t)i << 4) + (fq << 2));
        float s0 = __uint_as_float(sv.x << 16);
        float s1 = __uint_as_float(sv.x & 0xFFFF0000u);
        float s2 = __uint_as_float(sv.y << 16);
        float s3 = __uint_as_float(sv.y & 0xFFFF0000u);
        int f0 = fq << 2;
        float r0 = fmaxf(di * (acc.x + s0) + b1[f0 + 0], 0.f);
        float r1 = fmaxf(di * (acc.y + s1) + b1[f0 + 1], 0.f);
        float r2 = fmaxf(di * (acc.z + s2) + b1[f0 + 2], 0.f);
        float r3 = fmaxf(di * (acc.w + s3) + b1[f0 + 3], 0.f);
        v0 = r0 * W2[(f0 + 0) * 2] + r1 * W2[(f0 + 1) * 2] +
             r2 * W2[(f0 + 2) * 2] + r3 * W2[(f0 + 3) * 2];
        v1 = r0 * W2[(f0 + 0) * 2 + 1] + r1 * W2[(f0 + 1) * 2 + 1] +
             r2 * W2[(f0 + 2) * 2 + 1] + r3 * W2[(f0 + 3) * 2 + 1];
        // lanes fq=0..3 of this node are contiguous: width-4 xor reduce
        v0 += __shfl_xor(v0, 1, 4);
        v1 += __shfl_xor(v1, 1, 4);
        v0 += __shfl_xor(v0, 2, 4);
        v1 += __shfl_xor(v1, 2, 4);
        if (fq == 0) {
            float2 hv;
            hv.x = di * v0;
            hv.y = di * v1;
            *(float2*)(h2b + (size_t)i * 2) = hv;
        }
    }
}

// gather2: 4 lanes/node; o = di*(sum h2b[src] + h2b[i]) + b2; log_softmax.
__global__ __launch_bounds__(256) void k_gather2(const int* __restrict__ row_start,
                                                 const int* __restrict__ csr_src,
                                                 const float* __restrict__ dinv,
                                                 const float* __restrict__ h2b,
                                                 const float* __restrict__ b2,
                                                 float* __restrict__ out) {
    int t = threadIdx.x;
    int i = blockIdx.x * 64 + (t >> 2);
    int l = t & 3;
    int start = row_start[i];
    int end = row_start[i + 1];
    float di = dinv[i];
    float o0 = 0.f, o1 = 0.f;
    for (int e = start + l; e < end; e += 4) {
        int src = csr_src[e];
        float2 hv = *(const float2*)(h2b + (size_t)src * 2);
        o0 += hv.x;
        o1 += hv.y;
    }
    o0 += __shfl_xor(o0, 1, 4);
    o1 += __shfl_xor(o1, 1, 4);
    o0 += __shfl_xor(o0, 2, 4);
    o1 += __shfl_xor(o1, 2, 4);
    if (l == 0) {
        float2 hs = *(const float2*)(h2b + (size_t)i * 2);
        float f0 = di * (o0 + hs.x) + b2[0];
        float f1 = di * (o1 + hs.y) + b2[1];
        float m = fmaxf(f0, f1);
        float lse = m + logf(expf(f0 - m) + expf(f1 - m));
        out[(size_t)i * 2 + 0] = f0 - lse;
        out[(size_t)i * 2 + 1] = f1 - lse;
    }
}

extern "C" void kernel_launch(void* const* d_in, const int* in_sizes, int n_in,
                              void* d_out, int out_size, void* d_ws, size_t ws_size,
                              hipStream_t stream) {
    const float* x  = (const float*)d_in[0];
    const void*  ei = d_in[1];
    const float* W1 = (const float*)d_in[2];
    const float* b1 = (const float*)d_in[3];
    const float* W2 = (const float*)d_in[4];
    const float* b2 = (const float*)d_in[5];

    int*            wsw       = (int*)d_ws;
    float*          dinv      = (float*)(wsw + OFF_DINV);
    int*            row_start = wsw + OFF_ROW;
    int*            bcount    = wsw + OFF_BCOUNT;
    int*            bbase     = wsw + OFF_BBASE;
    int*            bcursor   = wsw + OFF_BCURSOR;
    int*            flag      = wsw + OFF_FLAG;
    unsigned*       ebuf      = (unsigned*)(wsw + OFF_EBUF);   // becomes csr_src
    unsigned short* h1b       = (unsigned short*)(wsw + OFF_H1B);
    float*          h2b       = (float*)(wsw + OFF_H2B);
    float*          out       = (float*)d_out;

    k_init<<<1, 256, 0, stream>>>(bcount, flag);
    k_detect<<<1, 256, 0, stream>>>(ei, flag);
    k_bhist<<<NCHUNK, 256, 0, stream>>>(ei, flag, bcount);
    k_bscan<<<1, 256, 0, stream>>>(bcount, bbase, bcursor, row_start);
    k_bscatter<<<NCHUNK, 256, 0, stream>>>(ei, flag, bcursor, ebuf);
    k_bsort<<<NB, 1024, 0, stream>>>(ebuf, bbase, row_start, dinv);
    k_gemm1<<<(N_NODES + 255) / 256, 256, 0, stream>>>(x, W1, dinv, h1b);
    k_gather1<<<N_NODES / 16, 256, 0, stream>>>(row_start, (const int*)ebuf, dinv, h1b, b1, W2, h2b);
    k_gather2<<<N_NODES / 64, 256, 0, stream>>>(row_start, (const int*)ebuf, dinv, h2b, b2, out);
}